// Round 1
// baseline (2887.558 us; speedup 1.0000x reference)
//
#include <hip/hip_runtime.h>

#define N_NODES 100000
#define N_EDGES 1600000
#define FT 128

// ---------------------------------------------------------------------------
// Kernel 1: dense projection  h[n][o] = sum_k x[n][k]*W[k][o] + b[o]
// Block = 256 threads, 8 rows per block, each thread computes 4 outputs.
// x rows staged in LDS (broadcast reads, conflict-free); W rows read as
// float4, coalesced 512B per k across each 32-lane group (L1/L2 resident,
// W is only 64 KiB).
// ---------------------------------------------------------------------------
__global__ __launch_bounds__(256) void gemm_bias_kernel(
    const float* __restrict__ x,
    const float* __restrict__ W,
    const float* __restrict__ b,
    float* __restrict__ h) {
  __shared__ float xs[8][FT];

  const int tid = threadIdx.x;
  const int rbase = blockIdx.x * 8;  // N_NODES % 8 == 0 -> no tail

  // Stage 8 rows of x (8*128 = 1024 floats = 256 float4) into LDS.
  {
    const float4* xsrc = (const float4*)(x + (size_t)rbase * FT);
    float4* xdst = (float4*)&xs[0][0];
    xdst[tid] = xsrc[tid];
  }
  __syncthreads();

  const int lrow = tid >> 5;         // 0..7
  const int o = (tid & 31) * 4;      // 0..124
  const int row = rbase + lrow;

  float acc0 = 0.f, acc1 = 0.f, acc2 = 0.f, acc3 = 0.f;
  const float* xr = xs[lrow];

#pragma unroll 8
  for (int k = 0; k < FT; ++k) {
    const float4 w = *(const float4*)(W + k * FT + o);
    const float xv = xr[k];  // LDS broadcast within the 32-lane group
    acc0 = fmaf(xv, w.x, acc0);
    acc1 = fmaf(xv, w.y, acc1);
    acc2 = fmaf(xv, w.z, acc2);
    acc3 = fmaf(xv, w.w, acc3);
  }

  const float4 bb = *(const float4*)(b + o);
  float4 r;
  r.x = acc0 + bb.x;
  r.y = acc1 + bb.y;
  r.z = acc2 + bb.z;
  r.w = acc3 + bb.w;
  *(float4*)(h + (size_t)row * FT + o) = r;
}

// ---------------------------------------------------------------------------
// Kernel 2: edge scatter  out[rows[e]] += vals[e] * h[cols[e]]
// 32 lanes per edge; float4 gather of the h row (coalesced 512B), 4 scalar
// fp32 atomicAdds per lane into the out row.
// ---------------------------------------------------------------------------
__global__ __launch_bounds__(256) void edge_scatter_kernel(
    const int* __restrict__ erows,
    const int* __restrict__ ecols,
    const float* __restrict__ evals,
    const float* __restrict__ h,
    float* out) {
  const int tid = threadIdx.x;
  const int e = blockIdx.x * 8 + (tid >> 5);
  if (e >= N_EDGES) return;

  const int r = erows[e];  // 32 lanes read same addr -> cache broadcast
  const int c = ecols[e];
  const float v = evals[e];

  const int j = (tid & 31) * 4;
  const float4 hv = *(const float4*)(h + (size_t)c * FT + j);
  float* op = out + (size_t)r * FT + j;
  atomicAdd(op + 0, v * hv.x);
  atomicAdd(op + 1, v * hv.y);
  atomicAdd(op + 2, v * hv.z);
  atomicAdd(op + 3, v * hv.w);
}

// ---------------------------------------------------------------------------
// Kernel 3: in-place ReLU on out (float4 vectorized).
// ---------------------------------------------------------------------------
__global__ __launch_bounds__(256) void relu_kernel(float* out, int n4) {
  const int i = blockIdx.x * blockDim.x + threadIdx.x;
  if (i < n4) {
    float4 v = ((float4*)out)[i];
    v.x = fmaxf(v.x, 0.f);
    v.y = fmaxf(v.y, 0.f);
    v.z = fmaxf(v.z, 0.f);
    v.w = fmaxf(v.w, 0.f);
    ((float4*)out)[i] = v;
  }
}

extern "C" void kernel_launch(void* const* d_in, const int* in_sizes, int n_in,
                              void* d_out, int out_size, void* d_ws, size_t ws_size,
                              hipStream_t stream) {
  const float* x = (const float*)d_in[0];
  const int* erows = (const int*)d_in[1];
  const int* ecols = (const int*)d_in[2];
  const float* evals = (const float*)d_in[3];
  const float* W = (const float*)d_in[4];
  const float* b = (const float*)d_in[5];
  float* out = (float*)d_out;
  float* h = (float*)d_ws;  // N_NODES*FT*4 = 51.2 MB scratch

  // out must start at zero for the atomic accumulation (harness poisons it).
  hipMemsetAsync(d_out, 0, (size_t)out_size * sizeof(float), stream);

  gemm_bias_kernel<<<N_NODES / 8, 256, 0, stream>>>(x, W, b, h);

  edge_scatter_kernel<<<(N_EDGES + 7) / 8, 256, 0, stream>>>(erows, ecols,
                                                             evals, h, out);

  const int n4 = out_size / 4;
  relu_kernel<<<(n4 + 255) / 256, 256, 0, stream>>>(out, n4);
}

// Round 2
// 701.807 us; speedup vs baseline: 4.1145x; 4.1145x over previous
//
#include <hip/hip_runtime.h>

#define N_NODES 100000
#define N_EDGES 1600000
#define FT 128

// ---- workspace layout (bytes) ----------------------------------------------
// h          [0,            51,200,000)   N_NODES*FT*4
// row_start  [51,200,000,   51,600,016)   (N_NODES+1) ints, padded
// cursor     [51,600,016,   52,000,016)   N_NODES ints (also used as counts)
// sorted_col [52,000,016,   58,400,016)   N_EDGES ints
// sorted_val [58,400,016,   64,800,016)   N_EDGES floats
#define OFF_H 0
#define OFF_ROWSTART 51200000
#define OFF_CURSOR 51600016
#define OFF_SCOL 52000016
#define OFF_SVAL 58400016
#define WS_NEEDED 64800016

// ---------------------------------------------------------------------------
// Kernel 1: dense projection  h[n][o] = sum_k x[n][k]*W[k][o] + b[o]
// ---------------------------------------------------------------------------
__global__ __launch_bounds__(256) void gemm_bias_kernel(
    const float* __restrict__ x,
    const float* __restrict__ W,
    const float* __restrict__ b,
    float* __restrict__ h) {
  __shared__ float xs[8][FT];

  const int tid = threadIdx.x;
  const int rbase = blockIdx.x * 8;  // N_NODES % 8 == 0 -> no tail

  {
    const float4* xsrc = (const float4*)(x + (size_t)rbase * FT);
    float4* xdst = (float4*)&xs[0][0];
    xdst[tid] = xsrc[tid];
  }
  __syncthreads();

  const int lrow = tid >> 5;
  const int o = (tid & 31) * 4;
  const int row = rbase + lrow;

  float acc0 = 0.f, acc1 = 0.f, acc2 = 0.f, acc3 = 0.f;
  const float* xr = xs[lrow];

#pragma unroll 8
  for (int k = 0; k < FT; ++k) {
    const float4 w = *(const float4*)(W + k * FT + o);
    const float xv = xr[k];
    acc0 = fmaf(xv, w.x, acc0);
    acc1 = fmaf(xv, w.y, acc1);
    acc2 = fmaf(xv, w.z, acc2);
    acc3 = fmaf(xv, w.w, acc3);
  }

  const float4 bb = *(const float4*)(b + o);
  float4 r;
  r.x = acc0 + bb.x;
  r.y = acc1 + bb.y;
  r.z = acc2 + bb.z;
  r.w = acc3 + bb.w;
  *(float4*)(h + (size_t)row * FT + o) = r;
}

// ---------------------------------------------------------------------------
// Kernel 2: row histogram (counts into `cursor`, pre-zeroed by memset).
// ---------------------------------------------------------------------------
__global__ __launch_bounds__(256) void hist_kernel(
    const int* __restrict__ erows, int* counts) {
  const int e = blockIdx.x * blockDim.x + threadIdx.x;
  if (e < N_EDGES) atomicAdd(&counts[erows[e]], 1);
}

// ---------------------------------------------------------------------------
// Kernel 3: single-block exclusive scan of counts -> row_start AND cursor.
// 1024 threads; thread t owns a contiguous chunk of ~98 counters.
// ---------------------------------------------------------------------------
__global__ __launch_bounds__(1024) void scan_kernel(
    int* __restrict__ counts,      // in: per-row counts (== cursor buffer)
    int* __restrict__ row_start) { // out: exclusive prefix, size N_NODES+1
  __shared__ int psum[1024];
  const int t = threadIdx.x;
  const int chunk = (N_NODES + 1023) / 1024;  // 98
  const int lo = t * chunk;
  const int hi = min(lo + chunk, N_NODES);

  int s = 0;
  for (int i = lo; i < hi; ++i) s += counts[i];
  psum[t] = s;
  __syncthreads();

  // Hillis-Steele inclusive scan over 1024 partials.
  for (int off = 1; off < 1024; off <<= 1) {
    int v = (t >= off) ? psum[t - off] : 0;
    __syncthreads();
    psum[t] += v;
    __syncthreads();
  }

  int run = (t == 0) ? 0 : psum[t - 1];  // exclusive base for this thread
  for (int i = lo; i < hi; ++i) {
    const int c = counts[i];
    row_start[i] = run;
    counts[i] = run;  // cursor init (same buffer)
    run += c;
  }
  if (t == 1023) row_start[N_NODES] = run;
}

// ---------------------------------------------------------------------------
// Kernel 4: scatter edges into CSR order using per-row cursors.
// ---------------------------------------------------------------------------
__global__ __launch_bounds__(256) void scatter_sort_kernel(
    const int* __restrict__ erows,
    const int* __restrict__ ecols,
    const float* __restrict__ evals,
    int* cursor,
    int* __restrict__ scol,
    float* __restrict__ sval) {
  const int e = blockIdx.x * blockDim.x + threadIdx.x;
  if (e >= N_EDGES) return;
  const int pos = atomicAdd(&cursor[erows[e]], 1);
  scol[pos] = ecols[e];
  sval[pos] = evals[e];
}

// ---------------------------------------------------------------------------
// Kernel 5: CSR SpMM + fused ReLU. One 32-lane group per output row;
// lane owns out[row][lane*4 .. lane*4+3]; edges accumulated in registers.
// ---------------------------------------------------------------------------
__global__ __launch_bounds__(256) void spmm_csr_kernel(
    const int* __restrict__ row_start,
    const int* __restrict__ scol,
    const float* __restrict__ sval,
    const float* __restrict__ h,
    float* __restrict__ out) {
  const int tid = threadIdx.x;
  const int row = blockIdx.x * 8 + (tid >> 5);
  if (row >= N_NODES) return;

  const int beg = row_start[row];
  const int end = row_start[row + 1];
  const int j = (tid & 31) * 4;

  float a0 = 0.f, a1 = 0.f, a2 = 0.f, a3 = 0.f;

  int e = beg;
  for (; e + 1 < end; e += 2) {
    const int c0 = scol[e];
    const float v0 = sval[e];
    const int c1 = scol[e + 1];
    const float v1 = sval[e + 1];
    const float4 h0 = *(const float4*)(h + (size_t)c0 * FT + j);
    const float4 h1 = *(const float4*)(h + (size_t)c1 * FT + j);
    a0 = fmaf(v0, h0.x, a0); a0 = fmaf(v1, h1.x, a0);
    a1 = fmaf(v0, h0.y, a1); a1 = fmaf(v1, h1.y, a1);
    a2 = fmaf(v0, h0.z, a2); a2 = fmaf(v1, h1.z, a2);
    a3 = fmaf(v0, h0.w, a3); a3 = fmaf(v1, h1.w, a3);
  }
  if (e < end) {
    const int c0 = scol[e];
    const float v0 = sval[e];
    const float4 h0 = *(const float4*)(h + (size_t)c0 * FT + j);
    a0 = fmaf(v0, h0.x, a0);
    a1 = fmaf(v0, h0.y, a1);
    a2 = fmaf(v0, h0.z, a2);
    a3 = fmaf(v0, h0.w, a3);
  }

  float4 r;
  r.x = fmaxf(a0, 0.f);
  r.y = fmaxf(a1, 0.f);
  r.z = fmaxf(a2, 0.f);
  r.w = fmaxf(a3, 0.f);
  *(float4*)(out + (size_t)row * FT + j) = r;
}

// ---------------------------------------------------------------------------
// Fallback (small ws): original atomic scatter + relu.
// ---------------------------------------------------------------------------
__global__ __launch_bounds__(256) void edge_scatter_kernel(
    const int* __restrict__ erows,
    const int* __restrict__ ecols,
    const float* __restrict__ evals,
    const float* __restrict__ h,
    float* out) {
  const int tid = threadIdx.x;
  const int e = blockIdx.x * 8 + (tid >> 5);
  if (e >= N_EDGES) return;
  const int r = erows[e];
  const int c = ecols[e];
  const float v = evals[e];
  const int j = (tid & 31) * 4;
  const float4 hv = *(const float4*)(h + (size_t)c * FT + j);
  float* op = out + (size_t)r * FT + j;
  atomicAdd(op + 0, v * hv.x);
  atomicAdd(op + 1, v * hv.y);
  atomicAdd(op + 2, v * hv.z);
  atomicAdd(op + 3, v * hv.w);
}

__global__ __launch_bounds__(256) void relu_kernel(float* out, int n4) {
  const int i = blockIdx.x * blockDim.x + threadIdx.x;
  if (i < n4) {
    float4 v = ((float4*)out)[i];
    v.x = fmaxf(v.x, 0.f);
    v.y = fmaxf(v.y, 0.f);
    v.z = fmaxf(v.z, 0.f);
    v.w = fmaxf(v.w, 0.f);
    ((float4*)out)[i] = v;
  }
}

extern "C" void kernel_launch(void* const* d_in, const int* in_sizes, int n_in,
                              void* d_out, int out_size, void* d_ws, size_t ws_size,
                              hipStream_t stream) {
  const float* x = (const float*)d_in[0];
  const int* erows = (const int*)d_in[1];
  const int* ecols = (const int*)d_in[2];
  const float* evals = (const float*)d_in[3];
  const float* W = (const float*)d_in[4];
  const float* b = (const float*)d_in[5];
  float* out = (float*)d_out;

  char* ws = (char*)d_ws;
  float* h = (float*)(ws + OFF_H);

  gemm_bias_kernel<<<N_NODES / 8, 256, 0, stream>>>(x, W, b, h);

  if (ws_size >= (size_t)WS_NEEDED) {
    int* row_start = (int*)(ws + OFF_ROWSTART);
    int* cursor = (int*)(ws + OFF_CURSOR);
    int* scol = (int*)(ws + OFF_SCOL);
    float* sval = (float*)(ws + OFF_SVAL);

    hipMemsetAsync(cursor, 0, N_NODES * sizeof(int), stream);
    hist_kernel<<<(N_EDGES + 255) / 256, 256, 0, stream>>>(erows, cursor);
    scan_kernel<<<1, 1024, 0, stream>>>(cursor, row_start);
    scatter_sort_kernel<<<(N_EDGES + 255) / 256, 256, 0, stream>>>(
        erows, ecols, evals, cursor, scol, sval);
    spmm_csr_kernel<<<(N_NODES + 7) / 8, 256, 0, stream>>>(row_start, scol,
                                                           sval, h, out);
  } else {
    hipMemsetAsync(d_out, 0, (size_t)out_size * sizeof(float), stream);
    edge_scatter_kernel<<<(N_EDGES + 7) / 8, 256, 0, stream>>>(erows, ecols,
                                                               evals, h, out);
    const int n4 = out_size / 4;
    relu_kernel<<<(n4 + 255) / 256, 256, 0, stream>>>(out, n4);
  }
}

// Round 3
// 494.574 us; speedup vs baseline: 5.8385x; 1.4190x over previous
//
#include <hip/hip_runtime.h>

#define N_NODES 100000
#define N_EDGES 1600000
#define FT 128

// ---- workspace layout (bytes) ----------------------------------------------
// h          [0,            51,200,000)   N_NODES*FT*4
// row_start  [51,200,000,   51,600,016)   (N_NODES+1) ints, padded
// cursor     [51,600,016,   52,000,016)   N_NODES ints (counts -> cursors)
// sorted_col [52,000,016,   58,400,016)   N_EDGES ints
// sorted_val [58,400,016,   64,800,016)   N_EDGES floats
// bsums      [64,800,016,   64,802,064)   512 ints (block partial sums)
#define OFF_H 0
#define OFF_ROWSTART 51200000
#define OFF_CURSOR 51600016
#define OFF_SCOL 52000016
#define OFF_SVAL 58400016
#define OFF_BSUMS 64800016
#define WS_NEEDED 64802064

#define SCAN_CHUNK 1024                                   // elements per block
#define SCAN_BLOCKS ((N_NODES + SCAN_CHUNK - 1) / SCAN_CHUNK)  // 98

// ---------------------------------------------------------------------------
// Kernel 1: dense projection  h[n][o] = sum_k x[n][k]*W[k][o] + b[o]
// ---------------------------------------------------------------------------
__global__ __launch_bounds__(256) void gemm_bias_kernel(
    const float* __restrict__ x,
    const float* __restrict__ W,
    const float* __restrict__ b,
    float* __restrict__ h) {
  __shared__ float xs[8][FT];

  const int tid = threadIdx.x;
  const int rbase = blockIdx.x * 8;  // N_NODES % 8 == 0 -> no tail

  {
    const float4* xsrc = (const float4*)(x + (size_t)rbase * FT);
    float4* xdst = (float4*)&xs[0][0];
    xdst[tid] = xsrc[tid];
  }
  __syncthreads();

  const int lrow = tid >> 5;
  const int o = (tid & 31) * 4;
  const int row = rbase + lrow;

  float acc0 = 0.f, acc1 = 0.f, acc2 = 0.f, acc3 = 0.f;
  const float* xr = xs[lrow];

#pragma unroll 8
  for (int k = 0; k < FT; ++k) {
    const float4 w = *(const float4*)(W + k * FT + o);
    const float xv = xr[k];
    acc0 = fmaf(xv, w.x, acc0);
    acc1 = fmaf(xv, w.y, acc1);
    acc2 = fmaf(xv, w.z, acc2);
    acc3 = fmaf(xv, w.w, acc3);
  }

  const float4 bb = *(const float4*)(b + o);
  float4 r;
  r.x = acc0 + bb.x;
  r.y = acc1 + bb.y;
  r.z = acc2 + bb.z;
  r.w = acc3 + bb.w;
  *(float4*)(h + (size_t)row * FT + o) = r;
}

// ---------------------------------------------------------------------------
// Kernel 2: row histogram (counts into `cursor`, pre-zeroed by memset).
// ---------------------------------------------------------------------------
__global__ __launch_bounds__(256) void hist_kernel(
    const int* __restrict__ erows, int* counts) {
  const int e = blockIdx.x * blockDim.x + threadIdx.x;
  if (e < N_EDGES) atomicAdd(&counts[erows[e]], 1);
}

// ---------------------------------------------------------------------------
// Scan phase 1: per-block sums of 1024 counts -> bsums[blockIdx].
// ---------------------------------------------------------------------------
__global__ __launch_bounds__(256) void scan1_kernel(
    const int* __restrict__ counts, int* __restrict__ bsums) {
  __shared__ int red[256];
  const int t = threadIdx.x;
  const int base = blockIdx.x * SCAN_CHUNK + t * 4;

  int s = 0;
#pragma unroll
  for (int i = 0; i < 4; ++i) {
    const int idx = base + i;
    if (idx < N_NODES) s += counts[idx];
  }
  red[t] = s;
  __syncthreads();
#pragma unroll
  for (int off = 128; off > 0; off >>= 1) {
    if (t < off) red[t] += red[t + off];
    __syncthreads();
  }
  if (t == 0) bsums[blockIdx.x] = red[0];
}

// ---------------------------------------------------------------------------
// Scan phase 2: one tiny block exclusive-scans the block sums in place.
// ---------------------------------------------------------------------------
__global__ __launch_bounds__(128) void scan2_kernel(int* __restrict__ bsums) {
  __shared__ int ps[128];
  const int t = threadIdx.x;
  int v = (t < SCAN_BLOCKS) ? bsums[t] : 0;
  ps[t] = v;
  __syncthreads();
#pragma unroll
  for (int off = 1; off < 128; off <<= 1) {
    const int u = (t >= off) ? ps[t - off] : 0;
    __syncthreads();
    ps[t] += u;
    __syncthreads();
  }
  if (t < SCAN_BLOCKS) bsums[t] = (t == 0) ? 0 : ps[t - 1];
}

// ---------------------------------------------------------------------------
// Scan phase 3: block-local exclusive scan + block offset. Writes row_start
// and cursor (cursor buffer == counts buffer; each element read-then-written
// by the same thread, so in-place is safe).
// ---------------------------------------------------------------------------
__global__ __launch_bounds__(256) void scan3_kernel(
    const int* __restrict__ counts,
    const int* __restrict__ bsums,
    int* __restrict__ row_start,
    int* __restrict__ cursor) {
  __shared__ int ts[256];
  const int t = threadIdx.x;
  const int base = blockIdx.x * SCAN_CHUNK + t * 4;

  int c[4];
  int s = 0;
#pragma unroll
  for (int i = 0; i < 4; ++i) {
    const int idx = base + i;
    c[i] = (idx < N_NODES) ? counts[idx] : 0;
    s += c[i];
  }
  ts[t] = s;
  __syncthreads();
#pragma unroll
  for (int off = 1; off < 256; off <<= 1) {
    const int u = (t >= off) ? ts[t - off] : 0;
    __syncthreads();
    ts[t] += u;
    __syncthreads();
  }

  int run = bsums[blockIdx.x] + ((t == 0) ? 0 : ts[t - 1]);
#pragma unroll
  for (int i = 0; i < 4; ++i) {
    const int idx = base + i;
    if (idx < N_NODES) {
      row_start[idx] = run;
      cursor[idx] = run;
      run += c[i];
    }
  }
  if (blockIdx.x == 0 && t == 0) row_start[N_NODES] = N_EDGES;
}

// ---------------------------------------------------------------------------
// Kernel 4: scatter edges into CSR order using per-row cursors.
// ---------------------------------------------------------------------------
__global__ __launch_bounds__(256) void scatter_sort_kernel(
    const int* __restrict__ erows,
    const int* __restrict__ ecols,
    const float* __restrict__ evals,
    int* cursor,
    int* __restrict__ scol,
    float* __restrict__ sval) {
  const int e = blockIdx.x * blockDim.x + threadIdx.x;
  if (e >= N_EDGES) return;
  const int pos = atomicAdd(&cursor[erows[e]], 1);
  scol[pos] = ecols[e];
  sval[pos] = evals[e];
}

// ---------------------------------------------------------------------------
// Kernel 5: CSR SpMM + fused ReLU. One 32-lane group per output row.
// ---------------------------------------------------------------------------
__global__ __launch_bounds__(256) void spmm_csr_kernel(
    const int* __restrict__ row_start,
    const int* __restrict__ scol,
    const float* __restrict__ sval,
    const float* __restrict__ h,
    float* __restrict__ out) {
  const int tid = threadIdx.x;
  const int row = blockIdx.x * 8 + (tid >> 5);
  if (row >= N_NODES) return;

  const int beg = row_start[row];
  const int end = row_start[row + 1];
  const int j = (tid & 31) * 4;

  float a0 = 0.f, a1 = 0.f, a2 = 0.f, a3 = 0.f;

  int e = beg;
  for (; e + 1 < end; e += 2) {
    const int c0 = scol[e];
    const float v0 = sval[e];
    const int c1 = scol[e + 1];
    const float v1 = sval[e + 1];
    const float4 h0 = *(const float4*)(h + (size_t)c0 * FT + j);
    const float4 h1 = *(const float4*)(h + (size_t)c1 * FT + j);
    a0 = fmaf(v0, h0.x, a0); a0 = fmaf(v1, h1.x, a0);
    a1 = fmaf(v0, h0.y, a1); a1 = fmaf(v1, h1.y, a1);
    a2 = fmaf(v0, h0.z, a2); a2 = fmaf(v1, h1.z, a2);
    a3 = fmaf(v0, h0.w, a3); a3 = fmaf(v1, h1.w, a3);
  }
  if (e < end) {
    const int c0 = scol[e];
    const float v0 = sval[e];
    const float4 h0 = *(const float4*)(h + (size_t)c0 * FT + j);
    a0 = fmaf(v0, h0.x, a0);
    a1 = fmaf(v0, h0.y, a1);
    a2 = fmaf(v0, h0.z, a2);
    a3 = fmaf(v0, h0.w, a3);
  }

  float4 r;
  r.x = fmaxf(a0, 0.f);
  r.y = fmaxf(a1, 0.f);
  r.z = fmaxf(a2, 0.f);
  r.w = fmaxf(a3, 0.f);
  *(float4*)(out + (size_t)row * FT + j) = r;
}

// ---------------------------------------------------------------------------
// Fallback (small ws): original atomic scatter + relu.
// ---------------------------------------------------------------------------
__global__ __launch_bounds__(256) void edge_scatter_kernel(
    const int* __restrict__ erows,
    const int* __restrict__ ecols,
    const float* __restrict__ evals,
    const float* __restrict__ h,
    float* out) {
  const int tid = threadIdx.x;
  const int e = blockIdx.x * 8 + (tid >> 5);
  if (e >= N_EDGES) return;
  const int r = erows[e];
  const int c = ecols[e];
  const float v = evals[e];
  const int j = (tid & 31) * 4;
  const float4 hv = *(const float4*)(h + (size_t)c * FT + j);
  float* op = out + (size_t)r * FT + j;
  atomicAdd(op + 0, v * hv.x);
  atomicAdd(op + 1, v * hv.y);
  atomicAdd(op + 2, v * hv.z);
  atomicAdd(op + 3, v * hv.w);
}

__global__ __launch_bounds__(256) void relu_kernel(float* out, int n4) {
  const int i = blockIdx.x * blockDim.x + threadIdx.x;
  if (i < n4) {
    float4 v = ((float4*)out)[i];
    v.x = fmaxf(v.x, 0.f);
    v.y = fmaxf(v.y, 0.f);
    v.z = fmaxf(v.z, 0.f);
    v.w = fmaxf(v.w, 0.f);
    ((float4*)out)[i] = v;
  }
}

extern "C" void kernel_launch(void* const* d_in, const int* in_sizes, int n_in,
                              void* d_out, int out_size, void* d_ws, size_t ws_size,
                              hipStream_t stream) {
  const float* x = (const float*)d_in[0];
  const int* erows = (const int*)d_in[1];
  const int* ecols = (const int*)d_in[2];
  const float* evals = (const float*)d_in[3];
  const float* W = (const float*)d_in[4];
  const float* b = (const float*)d_in[5];
  float* out = (float*)d_out;

  char* ws = (char*)d_ws;
  float* h = (float*)(ws + OFF_H);

  gemm_bias_kernel<<<N_NODES / 8, 256, 0, stream>>>(x, W, b, h);

  if (ws_size >= (size_t)WS_NEEDED) {
    int* row_start = (int*)(ws + OFF_ROWSTART);
    int* cursor = (int*)(ws + OFF_CURSOR);
    int* scol = (int*)(ws + OFF_SCOL);
    float* sval = (float*)(ws + OFF_SVAL);
    int* bsums = (int*)(ws + OFF_BSUMS);

    hipMemsetAsync(cursor, 0, N_NODES * sizeof(int), stream);
    hist_kernel<<<(N_EDGES + 255) / 256, 256, 0, stream>>>(erows, cursor);
    scan1_kernel<<<SCAN_BLOCKS, 256, 0, stream>>>(cursor, bsums);
    scan2_kernel<<<1, 128, 0, stream>>>(bsums);
    scan3_kernel<<<SCAN_BLOCKS, 256, 0, stream>>>(cursor, bsums, row_start,
                                                  cursor);
    scatter_sort_kernel<<<(N_EDGES + 255) / 256, 256, 0, stream>>>(
        erows, ecols, evals, cursor, scol, sval);
    spmm_csr_kernel<<<(N_NODES + 7) / 8, 256, 0, stream>>>(row_start, scol,
                                                           sval, h, out);
  } else {
    hipMemsetAsync(d_out, 0, (size_t)out_size * sizeof(float), stream);
    edge_scatter_kernel<<<(N_EDGES + 7) / 8, 256, 0, stream>>>(erows, ecols,
                                                               evals, h, out);
    const int n4 = out_size / 4;
    relu_kernel<<<(n4 + 255) / 256, 256, 0, stream>>>(out, n4);
  }
}

// Round 4
// 365.000 us; speedup vs baseline: 7.9111x; 1.3550x over previous
//
#include <hip/hip_runtime.h>

#define N_NODES 100000
#define N_EDGES 1600000
#define FT 128

// ---- workspace layout (bytes) ----------------------------------------------
// h          [0,            51,200,000)   N_NODES*FT*4
// row_start  [51,200,000,   51,600,016)   (N_NODES+1) ints, padded
// cursor     [51,600,016,   52,000,016)   N_NODES ints (counts -> cursors)
// sorted_col [52,000,016,   58,400,016)   N_EDGES ints
// sorted_val [58,400,016,   64,800,016)   N_EDGES floats
// bsums      [64,800,016,   64,802,064)   512 ints (block partial sums)
#define OFF_H 0
#define OFF_ROWSTART 51200000
#define OFF_CURSOR 51600016
#define OFF_SCOL 52000016
#define OFF_SVAL 58400016
#define OFF_BSUMS 64800016
#define WS_NEEDED 64802064

#define SCAN_CHUNK 1024
#define SCAN_BLOCKS ((N_NODES + SCAN_CHUNK - 1) / SCAN_CHUNK)  // 98

// ---------------------------------------------------------------------------
// Kernel 1: dense projection  h[n][o] = sum_k x[n][k]*W[k][o] + b[o]
// Register-tiled: block = 32 rows x 128 cols; thread = 4 rows x 4 cols.
// Per k: 1 float4 W load + 4 LDS broadcasts -> 16 FMAs.
// ---------------------------------------------------------------------------
__global__ __launch_bounds__(256) void gemm_bias_kernel(
    const float* __restrict__ x,
    const float* __restrict__ W,
    const float* __restrict__ b,
    float* __restrict__ h) {
  __shared__ float xs[32][FT];  // 16 KB

  const int tid = threadIdx.x;
  const int rbase = blockIdx.x * 32;  // 100000 % 32 == 0 -> no tail

  // Stage 32 rows of x (4096 floats = 1024 float4) into LDS.
  {
    const float4* xsrc = (const float4*)(x + (size_t)rbase * FT);
    float4* xdst = (float4*)&xs[0][0];
#pragma unroll
    for (int i = 0; i < 4; ++i) xdst[tid + 256 * i] = xsrc[tid + 256 * i];
  }
  __syncthreads();

  const int g = tid >> 5;        // 0..7  (row group)
  const int o = (tid & 31) * 4;  // col base 0..124
  const int r0 = g * 4;          // row base within tile

  float acc[4][4] = {{0.f}};

#pragma unroll 4
  for (int k = 0; k < FT; ++k) {
    const float4 w = *(const float4*)(W + k * FT + o);
#pragma unroll
    for (int i = 0; i < 4; ++i) {
      const float xv = xs[r0 + i][k];  // broadcast within 32-lane group
      acc[i][0] = fmaf(xv, w.x, acc[i][0]);
      acc[i][1] = fmaf(xv, w.y, acc[i][1]);
      acc[i][2] = fmaf(xv, w.z, acc[i][2]);
      acc[i][3] = fmaf(xv, w.w, acc[i][3]);
    }
  }

  const float4 bb = *(const float4*)(b + o);
#pragma unroll
  for (int i = 0; i < 4; ++i) {
    float4 r;
    r.x = acc[i][0] + bb.x;
    r.y = acc[i][1] + bb.y;
    r.z = acc[i][2] + bb.z;
    r.w = acc[i][3] + bb.w;
    *(float4*)(h + (size_t)(rbase + r0 + i) * FT + o) = r;
  }
}

// ---------------------------------------------------------------------------
// Kernel 2: row histogram (counts into `cursor`, pre-zeroed by memset).
// ---------------------------------------------------------------------------
__global__ __launch_bounds__(256) void hist_kernel(
    const int* __restrict__ erows, int* counts) {
  const int e = blockIdx.x * blockDim.x + threadIdx.x;
  if (e < N_EDGES) atomicAdd(&counts[erows[e]], 1);
}

// ---------------------------------------------------------------------------
// Scan phase 1: per-block sums of 1024 counts -> bsums[blockIdx].
// ---------------------------------------------------------------------------
__global__ __launch_bounds__(256) void scan1_kernel(
    const int* __restrict__ counts, int* __restrict__ bsums) {
  __shared__ int red[256];
  const int t = threadIdx.x;
  const int base = blockIdx.x * SCAN_CHUNK + t * 4;

  int s = 0;
#pragma unroll
  for (int i = 0; i < 4; ++i) {
    const int idx = base + i;
    if (idx < N_NODES) s += counts[idx];
  }
  red[t] = s;
  __syncthreads();
#pragma unroll
  for (int off = 128; off > 0; off >>= 1) {
    if (t < off) red[t] += red[t + off];
    __syncthreads();
  }
  if (t == 0) bsums[blockIdx.x] = red[0];
}

// ---------------------------------------------------------------------------
// Scan phase 2: one tiny block exclusive-scans the block sums in place.
// ---------------------------------------------------------------------------
__global__ __launch_bounds__(128) void scan2_kernel(int* __restrict__ bsums) {
  __shared__ int ps[128];
  const int t = threadIdx.x;
  int v = (t < SCAN_BLOCKS) ? bsums[t] : 0;
  ps[t] = v;
  __syncthreads();
#pragma unroll
  for (int off = 1; off < 128; off <<= 1) {
    const int u = (t >= off) ? ps[t - off] : 0;
    __syncthreads();
    ps[t] += u;
    __syncthreads();
  }
  if (t < SCAN_BLOCKS) bsums[t] = (t == 0) ? 0 : ps[t - 1];
}

// ---------------------------------------------------------------------------
// Scan phase 3: block-local exclusive scan + block offset -> row_start, cursor.
// ---------------------------------------------------------------------------
__global__ __launch_bounds__(256) void scan3_kernel(
    const int* __restrict__ counts,
    const int* __restrict__ bsums,
    int* __restrict__ row_start,
    int* __restrict__ cursor) {
  __shared__ int ts[256];
  const int t = threadIdx.x;
  const int base = blockIdx.x * SCAN_CHUNK + t * 4;

  int c[4];
  int s = 0;
#pragma unroll
  for (int i = 0; i < 4; ++i) {
    const int idx = base + i;
    c[i] = (idx < N_NODES) ? counts[idx] : 0;
    s += c[i];
  }
  ts[t] = s;
  __syncthreads();
#pragma unroll
  for (int off = 1; off < 256; off <<= 1) {
    const int u = (t >= off) ? ts[t - off] : 0;
    __syncthreads();
    ts[t] += u;
    __syncthreads();
  }

  int run = bsums[blockIdx.x] + ((t == 0) ? 0 : ts[t - 1]);
#pragma unroll
  for (int i = 0; i < 4; ++i) {
    const int idx = base + i;
    if (idx < N_NODES) {
      row_start[idx] = run;
      cursor[idx] = run;
      run += c[i];
    }
  }
  if (blockIdx.x == 0 && t == 0) row_start[N_NODES] = N_EDGES;
}

// ---------------------------------------------------------------------------
// Kernel 4: scatter edges into CSR order using per-row cursors.
// ---------------------------------------------------------------------------
__global__ __launch_bounds__(256) void scatter_sort_kernel(
    const int* __restrict__ erows,
    const int* __restrict__ ecols,
    const float* __restrict__ evals,
    int* cursor,
    int* __restrict__ scol,
    float* __restrict__ sval) {
  const int e = blockIdx.x * blockDim.x + threadIdx.x;
  if (e >= N_EDGES) return;
  const int pos = atomicAdd(&cursor[erows[e]], 1);
  scol[pos] = ecols[e];
  sval[pos] = evals[e];
}

// ---------------------------------------------------------------------------
// Kernel 5: CSR SpMM + fused ReLU. One 32-lane group per output row.
// ---------------------------------------------------------------------------
__global__ __launch_bounds__(256) void spmm_csr_kernel(
    const int* __restrict__ row_start,
    const int* __restrict__ scol,
    const float* __restrict__ sval,
    const float* __restrict__ h,
    float* __restrict__ out) {
  const int tid = threadIdx.x;
  const int row = blockIdx.x * 8 + (tid >> 5);
  if (row >= N_NODES) return;

  const int beg = row_start[row];
  const int end = row_start[row + 1];
  const int j = (tid & 31) * 4;

  float a0 = 0.f, a1 = 0.f, a2 = 0.f, a3 = 0.f;

  int e = beg;
  for (; e + 1 < end; e += 2) {
    const int c0 = scol[e];
    const float v0 = sval[e];
    const int c1 = scol[e + 1];
    const float v1 = sval[e + 1];
    const float4 h0 = *(const float4*)(h + (size_t)c0 * FT + j);
    const float4 h1 = *(const float4*)(h + (size_t)c1 * FT + j);
    a0 = fmaf(v0, h0.x, a0); a0 = fmaf(v1, h1.x, a0);
    a1 = fmaf(v0, h0.y, a1); a1 = fmaf(v1, h1.y, a1);
    a2 = fmaf(v0, h0.z, a2); a2 = fmaf(v1, h1.z, a2);
    a3 = fmaf(v0, h0.w, a3); a3 = fmaf(v1, h1.w, a3);
  }
  if (e < end) {
    const int c0 = scol[e];
    const float v0 = sval[e];
    const float4 h0 = *(const float4*)(h + (size_t)c0 * FT + j);
    a0 = fmaf(v0, h0.x, a0);
    a1 = fmaf(v0, h0.y, a1);
    a2 = fmaf(v0, h0.z, a2);
    a3 = fmaf(v0, h0.w, a3);
  }

  float4 r;
  r.x = fmaxf(a0, 0.f);
  r.y = fmaxf(a1, 0.f);
  r.z = fmaxf(a2, 0.f);
  r.w = fmaxf(a3, 0.f);
  *(float4*)(out + (size_t)row * FT + j) = r;
}

// ---------------------------------------------------------------------------
// Fallback (small ws): original atomic scatter + relu.
// ---------------------------------------------------------------------------
__global__ __launch_bounds__(256) void edge_scatter_kernel(
    const int* __restrict__ erows,
    const int* __restrict__ ecols,
    const float* __restrict__ evals,
    const float* __restrict__ h,
    float* out) {
  const int tid = threadIdx.x;
  const int e = blockIdx.x * 8 + (tid >> 5);
  if (e >= N_EDGES) return;
  const int r = erows[e];
  const int c = ecols[e];
  const float v = evals[e];
  const int j = (tid & 31) * 4;
  const float4 hv = *(const float4*)(h + (size_t)c * FT + j);
  float* op = out + (size_t)r * FT + j;
  atomicAdd(op + 0, v * hv.x);
  atomicAdd(op + 1, v * hv.y);
  atomicAdd(op + 2, v * hv.z);
  atomicAdd(op + 3, v * hv.w);
}

__global__ __launch_bounds__(256) void relu_kernel(float* out, int n4) {
  const int i = blockIdx.x * blockDim.x + threadIdx.x;
  if (i < n4) {
    float4 v = ((float4*)out)[i];
    v.x = fmaxf(v.x, 0.f);
    v.y = fmaxf(v.y, 0.f);
    v.z = fmaxf(v.z, 0.f);
    v.w = fmaxf(v.w, 0.f);
    ((float4*)out)[i] = v;
  }
}

extern "C" void kernel_launch(void* const* d_in, const int* in_sizes, int n_in,
                              void* d_out, int out_size, void* d_ws, size_t ws_size,
                              hipStream_t stream) {
  const float* x = (const float*)d_in[0];
  const int* erows = (const int*)d_in[1];
  const int* ecols = (const int*)d_in[2];
  const float* evals = (const float*)d_in[3];
  const float* W = (const float*)d_in[4];
  const float* b = (const float*)d_in[5];
  float* out = (float*)d_out;

  char* ws = (char*)d_ws;
  float* h = (float*)(ws + OFF_H);

  gemm_bias_kernel<<<N_NODES / 32, 256, 0, stream>>>(x, W, b, h);

  if (ws_size >= (size_t)WS_NEEDED) {
    int* row_start = (int*)(ws + OFF_ROWSTART);
    int* cursor = (int*)(ws + OFF_CURSOR);
    int* scol = (int*)(ws + OFF_SCOL);
    float* sval = (float*)(ws + OFF_SVAL);
    int* bsums = (int*)(ws + OFF_BSUMS);

    hipMemsetAsync(cursor, 0, N_NODES * sizeof(int), stream);
    hist_kernel<<<(N_EDGES + 255) / 256, 256, 0, stream>>>(erows, cursor);
    scan1_kernel<<<SCAN_BLOCKS, 256, 0, stream>>>(cursor, bsums);
    scan2_kernel<<<1, 128, 0, stream>>>(bsums);
    scan3_kernel<<<SCAN_BLOCKS, 256, 0, stream>>>(cursor, bsums, row_start,
                                                  cursor);
    scatter_sort_kernel<<<(N_EDGES + 255) / 256, 256, 0, stream>>>(
        erows, ecols, evals, cursor, scol, sval);
    spmm_csr_kernel<<<(N_NODES + 7) / 8, 256, 0, stream>>>(row_start, scol,
                                                           sval, h, out);
  } else {
    hipMemsetAsync(d_out, 0, (size_t)out_size * sizeof(float), stream);
    edge_scatter_kernel<<<(N_EDGES + 7) / 8, 256, 0, stream>>>(erows, ecols,
                                                               evals, h, out);
    const int n4 = out_size / 4;
    relu_kernel<<<(n4 + 255) / 256, 256, 0, stream>>>(out, n4);
  }
}

// Round 5
// 361.390 us; speedup vs baseline: 7.9901x; 1.0100x over previous
//
#include <hip/hip_runtime.h>

#define N_NODES 100000
#define N_EDGES 1600000
#define FT 128

// ---- workspace layout (bytes) ----------------------------------------------
// h          [0,            51,200,000)   N_NODES*FT*4
// row_start  [51,200,000,   51,600,016)   (N_NODES+1) ints, padded
// cursor     [51,600,016,   52,000,016)   N_NODES ints (counts -> cursors)
// sorted     [52,000,016,   64,800,016)   N_EDGES int2 (col, val_bits)
// bsums      [64,800,016,   64,802,064)   512 ints (block partial sums)
#define OFF_H 0
#define OFF_ROWSTART 51200000
#define OFF_CURSOR 51600016
#define OFF_SORTED 52000016
#define OFF_BSUMS 64800016
#define WS_NEEDED 64802064

#define SCAN_CHUNK 1024
#define SCAN_BLOCKS ((N_NODES + SCAN_CHUNK - 1) / SCAN_CHUNK)  // 98

// ---------------------------------------------------------------------------
// Kernel 1: dense projection  h[n][o] = sum_k x[n][k]*W[k][o] + b[o]
// Register-tiled: block = 32 rows x 128 cols; thread = 4 rows x 4 cols.
// ---------------------------------------------------------------------------
__global__ __launch_bounds__(256) void gemm_bias_kernel(
    const float* __restrict__ x,
    const float* __restrict__ W,
    const float* __restrict__ b,
    float* __restrict__ h) {
  __shared__ float xs[32][FT];  // 16 KB

  const int tid = threadIdx.x;
  const int rbase = blockIdx.x * 32;  // 100000 % 32 == 0 -> no tail

  {
    const float4* xsrc = (const float4*)(x + (size_t)rbase * FT);
    float4* xdst = (float4*)&xs[0][0];
#pragma unroll
    for (int i = 0; i < 4; ++i) xdst[tid + 256 * i] = xsrc[tid + 256 * i];
  }
  __syncthreads();

  const int g = tid >> 5;        // 0..7  (row group)
  const int o = (tid & 31) * 4;  // col base 0..124
  const int r0 = g * 4;          // row base within tile

  float acc[4][4] = {{0.f}};

#pragma unroll 4
  for (int k = 0; k < FT; ++k) {
    const float4 w = *(const float4*)(W + k * FT + o);
#pragma unroll
    for (int i = 0; i < 4; ++i) {
      const float xv = xs[r0 + i][k];  // broadcast within 32-lane group
      acc[i][0] = fmaf(xv, w.x, acc[i][0]);
      acc[i][1] = fmaf(xv, w.y, acc[i][1]);
      acc[i][2] = fmaf(xv, w.z, acc[i][2]);
      acc[i][3] = fmaf(xv, w.w, acc[i][3]);
    }
  }

  const float4 bb = *(const float4*)(b + o);
#pragma unroll
  for (int i = 0; i < 4; ++i) {
    float4 r;
    r.x = acc[i][0] + bb.x;
    r.y = acc[i][1] + bb.y;
    r.z = acc[i][2] + bb.z;
    r.w = acc[i][3] + bb.w;
    *(float4*)(h + (size_t)(rbase + r0 + i) * FT + o) = r;
  }
}

// ---------------------------------------------------------------------------
// Kernel 2: row histogram (counts pre-zeroed by memset). int4 edge reads.
// ---------------------------------------------------------------------------
__global__ __launch_bounds__(256) void hist_kernel(
    const int* __restrict__ erows, int* counts) {
  const int i = blockIdx.x * blockDim.x + threadIdx.x;  // i indexes int4
  if (i * 4 >= N_EDGES) return;
  const int4 r = ((const int4*)erows)[i];
  atomicAdd(&counts[r.x], 1);
  atomicAdd(&counts[r.y], 1);
  atomicAdd(&counts[r.z], 1);
  atomicAdd(&counts[r.w], 1);
}

// ---------------------------------------------------------------------------
// Scan phase 1: per-block sums of 1024 counts -> bsums[blockIdx].
// ---------------------------------------------------------------------------
__global__ __launch_bounds__(256) void scan1_kernel(
    const int* __restrict__ counts, int* __restrict__ bsums) {
  __shared__ int red[256];
  const int t = threadIdx.x;
  const int idx4 = blockIdx.x * 256 + t;  // int4 index

  int s = 0;
  if (idx4 * 4 < N_NODES) {
    const int4 c = ((const int4*)counts)[idx4];
    // tail-safe: N_NODES % 4 == 0, so full int4 is fine
    s = c.x + c.y + c.z + c.w;
  }
  red[t] = s;
  __syncthreads();
#pragma unroll
  for (int off = 128; off > 0; off >>= 1) {
    if (t < off) red[t] += red[t + off];
    __syncthreads();
  }
  if (t == 0) bsums[blockIdx.x] = red[0];
}

// ---------------------------------------------------------------------------
// Scan phase 2: one tiny block exclusive-scans the block sums in place.
// ---------------------------------------------------------------------------
__global__ __launch_bounds__(128) void scan2_kernel(int* __restrict__ bsums) {
  __shared__ int ps[128];
  const int t = threadIdx.x;
  int v = (t < SCAN_BLOCKS) ? bsums[t] : 0;
  ps[t] = v;
  __syncthreads();
#pragma unroll
  for (int off = 1; off < 128; off <<= 1) {
    const int u = (t >= off) ? ps[t - off] : 0;
    __syncthreads();
    ps[t] += u;
    __syncthreads();
  }
  if (t < SCAN_BLOCKS) bsums[t] = (t == 0) ? 0 : ps[t - 1];
}

// ---------------------------------------------------------------------------
// Scan phase 3: block-local exclusive scan + block offset -> row_start, cursor.
// ---------------------------------------------------------------------------
__global__ __launch_bounds__(256) void scan3_kernel(
    const int* __restrict__ counts,
    const int* __restrict__ bsums,
    int* __restrict__ row_start,
    int* __restrict__ cursor) {
  __shared__ int ts[256];
  const int t = threadIdx.x;
  const int idx4 = blockIdx.x * 256 + t;
  const int base = idx4 * 4;

  int4 c = {0, 0, 0, 0};
  if (base < N_NODES) c = ((const int4*)counts)[idx4];  // N_NODES % 4 == 0
  const int s = c.x + c.y + c.z + c.w;
  ts[t] = s;
  __syncthreads();
#pragma unroll
  for (int off = 1; off < 256; off <<= 1) {
    const int u = (t >= off) ? ts[t - off] : 0;
    __syncthreads();
    ts[t] += u;
    __syncthreads();
  }

  if (base < N_NODES) {
    int run = bsums[blockIdx.x] + ((t == 0) ? 0 : ts[t - 1]);
    int4 rs, cu;
    rs.x = run; cu.x = run; run += c.x;
    rs.y = run; cu.y = run; run += c.y;
    rs.z = run; cu.z = run; run += c.z;
    rs.w = run; cu.w = run; run += c.w;
    ((int4*)row_start)[idx4] = rs;  // row_start base is 16B-aligned
    ((int4*)cursor)[idx4] = cu;
  }
  if (blockIdx.x == 0 && t == 0) row_start[N_NODES] = N_EDGES;
}

// ---------------------------------------------------------------------------
// Kernel 4: scatter edges into CSR order; single packed 8B write per edge.
// ---------------------------------------------------------------------------
__global__ __launch_bounds__(256) void scatter_sort_kernel(
    const int* __restrict__ erows,
    const int* __restrict__ ecols,
    const float* __restrict__ evals,
    int* cursor,
    int2* __restrict__ sorted) {
  const int e = blockIdx.x * blockDim.x + threadIdx.x;
  if (e >= N_EDGES) return;
  const int pos = atomicAdd(&cursor[erows[e]], 1);
  int2 p;
  p.x = ecols[e];
  p.y = __float_as_int(evals[e]);
  sorted[pos] = p;
}

// ---------------------------------------------------------------------------
// Kernel 5: CSR SpMM + fused ReLU. One 32-lane group per output row.
// ---------------------------------------------------------------------------
__global__ __launch_bounds__(256) void spmm_csr_kernel(
    const int* __restrict__ row_start,
    const int2* __restrict__ sorted,
    const float* __restrict__ h,
    float* __restrict__ out) {
  const int tid = threadIdx.x;
  const int row = blockIdx.x * 8 + (tid >> 5);
  if (row >= N_NODES) return;

  const int beg = row_start[row];
  const int end = row_start[row + 1];
  const int j = (tid & 31) * 4;

  float a0 = 0.f, a1 = 0.f, a2 = 0.f, a3 = 0.f;

  int e = beg;
  for (; e + 1 < end; e += 2) {
    const int2 p0 = sorted[e];
    const int2 p1 = sorted[e + 1];
    const float v0 = __int_as_float(p0.y);
    const float v1 = __int_as_float(p1.y);
    const float4 h0 = *(const float4*)(h + (size_t)p0.x * FT + j);
    const float4 h1 = *(const float4*)(h + (size_t)p1.x * FT + j);
    a0 = fmaf(v0, h0.x, a0); a0 = fmaf(v1, h1.x, a0);
    a1 = fmaf(v0, h0.y, a1); a1 = fmaf(v1, h1.y, a1);
    a2 = fmaf(v0, h0.z, a2); a2 = fmaf(v1, h1.z, a2);
    a3 = fmaf(v0, h0.w, a3); a3 = fmaf(v1, h1.w, a3);
  }
  if (e < end) {
    const int2 p0 = sorted[e];
    const float v0 = __int_as_float(p0.y);
    const float4 h0 = *(const float4*)(h + (size_t)p0.x * FT + j);
    a0 = fmaf(v0, h0.x, a0);
    a1 = fmaf(v0, h0.y, a1);
    a2 = fmaf(v0, h0.z, a2);
    a3 = fmaf(v0, h0.w, a3);
  }

  float4 r;
  r.x = fmaxf(a0, 0.f);
  r.y = fmaxf(a1, 0.f);
  r.z = fmaxf(a2, 0.f);
  r.w = fmaxf(a3, 0.f);
  *(float4*)(out + (size_t)row * FT + j) = r;
}

// ---------------------------------------------------------------------------
// Fallback (small ws): atomic scatter + relu.
// ---------------------------------------------------------------------------
__global__ __launch_bounds__(256) void edge_scatter_kernel(
    const int* __restrict__ erows,
    const int* __restrict__ ecols,
    const float* __restrict__ evals,
    const float* __restrict__ h,
    float* out) {
  const int tid = threadIdx.x;
  const int e = blockIdx.x * 8 + (tid >> 5);
  if (e >= N_EDGES) return;
  const int r = erows[e];
  const int c = ecols[e];
  const float v = evals[e];
  const int j = (tid & 31) * 4;
  const float4 hv = *(const float4*)(h + (size_t)c * FT + j);
  float* op = out + (size_t)r * FT + j;
  atomicAdd(op + 0, v * hv.x);
  atomicAdd(op + 1, v * hv.y);
  atomicAdd(op + 2, v * hv.z);
  atomicAdd(op + 3, v * hv.w);
}

__global__ __launch_bounds__(256) void relu_kernel(float* out, int n4) {
  const int i = blockIdx.x * blockDim.x + threadIdx.x;
  if (i < n4) {
    float4 v = ((float4*)out)[i];
    v.x = fmaxf(v.x, 0.f);
    v.y = fmaxf(v.y, 0.f);
    v.z = fmaxf(v.z, 0.f);
    v.w = fmaxf(v.w, 0.f);
    ((float4*)out)[i] = v;
  }
}

extern "C" void kernel_launch(void* const* d_in, const int* in_sizes, int n_in,
                              void* d_out, int out_size, void* d_ws, size_t ws_size,
                              hipStream_t stream) {
  const float* x = (const float*)d_in[0];
  const int* erows = (const int*)d_in[1];
  const int* ecols = (const int*)d_in[2];
  const float* evals = (const float*)d_in[3];
  const float* W = (const float*)d_in[4];
  const float* b = (const float*)d_in[5];
  float* out = (float*)d_out;

  char* ws = (char*)d_ws;
  float* h = (float*)(ws + OFF_H);

  gemm_bias_kernel<<<N_NODES / 32, 256, 0, stream>>>(x, W, b, h);

  if (ws_size >= (size_t)WS_NEEDED) {
    int* row_start = (int*)(ws + OFF_ROWSTART);
    int* cursor = (int*)(ws + OFF_CURSOR);
    int2* sorted = (int2*)(ws + OFF_SORTED);
    int* bsums = (int*)(ws + OFF_BSUMS);

    hipMemsetAsync(cursor, 0, N_NODES * sizeof(int), stream);
    hist_kernel<<<(N_EDGES / 4 + 255) / 256, 256, 0, stream>>>(erows, cursor);
    scan1_kernel<<<SCAN_BLOCKS, 256, 0, stream>>>(cursor, bsums);
    scan2_kernel<<<1, 128, 0, stream>>>(bsums);
    scan3_kernel<<<SCAN_BLOCKS, 256, 0, stream>>>(cursor, bsums, row_start,
                                                  cursor);
    scatter_sort_kernel<<<(N_EDGES + 255) / 256, 256, 0, stream>>>(
        erows, ecols, evals, cursor, sorted);
    spmm_csr_kernel<<<(N_NODES + 7) / 8, 256, 0, stream>>>(row_start, sorted,
                                                           h, out);
  } else {
    hipMemsetAsync(d_out, 0, (size_t)out_size * sizeof(float), stream);
    edge_scatter_kernel<<<(N_EDGES + 7) / 8, 256, 0, stream>>>(erows, ecols,
                                                               evals, h, out);
    const int n4 = out_size / 4;
    relu_kernel<<<(n4 + 255) / 256, 256, 0, stream>>>(out, n4);
  }
}